// Round 17
// baseline (256.400 us; speedup 1.0000x reference)
//
#include <hip/hip_runtime.h>
#include <hip/hip_bf16.h>

#define BATCH 4
#define LSEQ 4096
#define DMODEL 1024
#define NHEAD 16
#define RDIM 30
#define DKH 64
#define NCHUNK 32
#define CHUNK 128

typedef __attribute__((ext_vector_type(8))) short bf16x8_t;
typedef __attribute__((ext_vector_type(4))) float f32x4_t;

static __device__ __forceinline__ unsigned short f2bf(float f) {
    __hip_bfloat16 h = __float2bfloat16(f);
    unsigned short u;
    __builtin_memcpy(&u, &h, 2);
    return u;
}
static __device__ __forceinline__ float b2f(unsigned short u) {
    unsigned v = ((unsigned)u) << 16;
    float f;
    __builtin_memcpy(&f, &v, 4);
    return f;
}

#define SWAIT_VM12()  { asm volatile("s_waitcnt vmcnt(12)" ::: "memory"); __builtin_amdgcn_sched_barrier(0); }
#define SWAIT_VM8()   { asm volatile("s_waitcnt vmcnt(8)" ::: "memory"); __builtin_amdgcn_sched_barrier(0); }
#define SWAIT_VM4()   { asm volatile("s_waitcnt vmcnt(4)" ::: "memory"); __builtin_amdgcn_sched_barrier(0); }
#define SWAIT_VM0()   { asm volatile("s_waitcnt vmcnt(0)" ::: "memory"); __builtin_amdgcn_sched_barrier(0); }
#define SWAIT_LGKM0() { asm volatile("s_waitcnt lgkmcnt(0)" ::: "memory"); __builtin_amdgcn_sched_barrier(0); }
#define SBARRIER()    { __builtin_amdgcn_s_barrier(); __builtin_amdgcn_sched_barrier(0); }

// ---------------- transpose + convert: W (K,N) f32 -> Wt (N,K) bf16 (z: Wq/Wk) ----------------
__global__ void transpose_cvt_kernel(const float* __restrict__ W0, const float* __restrict__ W1,
                                     unsigned short* __restrict__ O0, unsigned short* __restrict__ O1) {
    __shared__ float tile[32][33];
    const float* W = blockIdx.z ? W1 : W0;
    unsigned short* outT = blockIdx.z ? O1 : O0;
    int n0 = blockIdx.x * 32, k0 = blockIdx.y * 32;
    int tx = threadIdx.x, ty = threadIdx.y;
    #pragma unroll
    for (int r = ty; r < 32; r += 8)
        tile[r][tx] = W[(size_t)(k0 + r) * DMODEL + n0 + tx];
    __syncthreads();
    #pragma unroll
    for (int r = ty; r < 32; r += 8)
        outT[(size_t)(n0 + r) * DMODEL + k0 + tx] = f2bf(tile[tx][r]);
}

// ---------------- wpack: We/Wr [H][64][30] f32 -> WP [H][32 cols][64 k] bf16 ----------------
__global__ void wpack_kernel(const float* __restrict__ We, const float* __restrict__ Wr,
                             unsigned short* __restrict__ WeP, unsigned short* __restrict__ WrP) {
    int h = blockIdx.x;
    const float* W = blockIdx.y ? Wr : We;
    unsigned short* O = blockIdx.y ? WrP : WeP;
    for (int idx = threadIdx.x; idx < 2048; idx += 256) {
        int col = idx >> 6, k = idx & 63;
        float v = (col < RDIM) ? W[((size_t)h * 64 + k) * RDIM + col] : 0.f;
        O[((size_t)h << 11) + idx] = f2bf(v);
    }
}

// ---------------- bias2[n] = bo[n] + sum_d bc[d&63]*Wo[d][n]  (parallel d-groups + LDS reduce) ----------------
__global__ __launch_bounds__(256) void bias2_kernel(
    const float* __restrict__ Wo, const float* __restrict__ bc,
    const float* __restrict__ bo, float* __restrict__ bias2) {
    __shared__ float red[4][64];
    const int n = blockIdx.x * 64 + (threadIdx.x & 63);
    const int dg = threadIdx.x >> 6;              // 0..3, each covers 256 d's
    float a = 0.f;
    #pragma unroll 4
    for (int d = dg * 256; d < dg * 256 + 256; ++d)
        a = fmaf(bc[d & 63], Wo[(size_t)d * DMODEL + n], a);
    red[dg][threadIdx.x & 63] = a;
    __syncthreads();
    if (dg == 0)
        bias2[n] = bo[n] + red[0][threadIdx.x] + red[1][threadIdx.x]
                         + red[2][threadIdx.x] + red[3][threadIdx.x];
}

// ---------------- WfoldT[n][h*64+j] = sum_dk Wc[jr][dk] * Wo[h*64+dk][n]  (bf16, K=1024 padded) ----------------
__global__ __launch_bounds__(256) void wfold_kernel(
    const float* __restrict__ Wc, const float* __restrict__ Wo,
    unsigned short* __restrict__ WfoldT)
{
    __shared__ float WoT[64][65];
    __shared__ float WcT[64][61];
    const int tid = threadIdx.x;
    const int n0 = blockIdx.x * 64, h = blockIdx.y;
    for (int i = tid; i < 4096; i += 256) {
        int dk = i >> 6, n = i & 63;
        WoT[dk][n] = Wo[(size_t)(h * 64 + dk) * DMODEL + n0 + n];
    }
    for (int i = tid; i < 3840; i += 256) {
        int j = i >> 6, dk = i & 63;
        WcT[dk][j] = Wc[j * 64 + dk];
    }
    __syncthreads();
    #pragma unroll 1
    for (int oo = 0; oo < 16; ++oo) {
        int n = (tid >> 6) + oo * 4;
        int j = tid & 63;
        int jr = (j < 30) ? j : (j >= 32 && j < 62) ? (j - 2) : -1;
        float acc = 0.f;
        if (jr >= 0) {
            #pragma unroll
            for (int dk = 0; dk < 64; ++dk)
                acc = fmaf(WcT[dk][jr], WoT[dk][n], acc);
        }
        WfoldT[(size_t)(n0 + n) * 1024 + h * 64 + j] = f2bf(acc);
    }
}

// ================= 256x256 8-wave counted-vmcnt GEMM =================
// AF32 path (QK): single-lgkm-drain reorder — A_WRITE+A_ISSUE at iter top
// (full-iteration load-to-wait distance), both MFMA clusters overlap traffic.
// !AF32 path (final GEMM): WIDE tile body (R16-proven).
#define GBM 256
#define GBN 256

template <bool AF32, bool BF16_OUT, bool DOCUM, int KD>
__global__ __launch_bounds__(512, 2) void gemm8_kernel(
    const void* __restrict__ Av0, const void* __restrict__ Av1,
    const unsigned short* __restrict__ Bt0, const unsigned short* __restrict__ Bt1,
    const float* __restrict__ bias0, const float* __restrict__ bias1,
    void* __restrict__ Cv0, void* __restrict__ Cv1,
    float* __restrict__ part0, float* __restrict__ part1,
    int N)
{
    constexpr int NT = KD / 64;
    __shared__ __align__(16) unsigned short As[2][GBM * 64];
    __shared__ __align__(16) unsigned short Bs[2][GBM * 64];
    const int tid = threadIdx.x;
    const int lane = tid & 63;
    const int wid = tid >> 6;        // 0..7
    const int wm = wid >> 2;         // 0..1
    const int wn = wid & 3;          // 0..3
    const int lm = lane & 15;
    const int kb = lane >> 4;        // 0..3
    const int z = blockIdx.z;

    const void* Av = z ? Av1 : Av0;
    const unsigned short* Bt = z ? Bt1 : Bt0;
    const float* bias = z ? bias1 : bias0;
    void* Cv = z ? Cv1 : Cv0;
    float* part = z ? part1 : part0;

    // bijective XCD chunking per z-slice (nwg = 4*64 = 256, %8 == 0)
    const int nwg = gridDim.x * gridDim.y;
    const int wg = blockIdx.y * gridDim.x + blockIdx.x;
    const int cpx = nwg >> 3;
    const int swz = (wg & 7) * cpx + (wg >> 3);
    const int bn = swz % gridDim.x;
    const int bm = swz / gridDim.x;

    const unsigned short* Btile = Bt + (size_t)(bn * GBN) * KD;
    const float* A32_tile = nullptr;
    const unsigned short* A16_tile = nullptr;
    if constexpr (AF32) A32_tile = (const float*)Av + (size_t)(bm * GBM) * KD;
    else                A16_tile = (const unsigned short*)Av + (size_t)(bm * GBM) * KD;

    f32x4_t acc[8][4];
    #pragma unroll
    for (int i = 0; i < 8; ++i)
        #pragma unroll
        for (int j = 0; j < 4; ++j)
            acc[i][j] = f32x4_t{0.f, 0.f, 0.f, 0.f};

    auto B_STAGE = [&](int buf, int kt) {
        #pragma unroll
        for (int seg = 0; seg < 4; ++seg) {
            const int s = (seg << 13) + (tid << 4);
            const int row = s >> 7;
            const int cc = ((s >> 4) & 7) ^ (row & 7);   // T2 pre-swizzled source, linear dest
            const unsigned short* gb = Btile + (size_t)row * KD + kt * 64 + cc * 8;
            __builtin_amdgcn_global_load_lds(
                (const __attribute__((address_space(1))) void*)gb,
                (__attribute__((address_space(3))) void*)((char*)&Bs[buf][0] + (seg << 13) + (wid << 10)),
                16, 0, 0);
        }
    };
    auto A_STAGE16 = [&](int buf, int kt) {
        #pragma unroll
        for (int seg = 0; seg < 4; ++seg) {
            const int s = (seg << 13) + (tid << 4);
            const int row = s >> 7;
            const int cc = ((s >> 4) & 7) ^ (row & 7);
            const unsigned short* ga = A16_tile + (size_t)row * KD + kt * 64 + cc * 8;
            __builtin_amdgcn_global_load_lds(
                (const __attribute__((address_space(1))) void*)ga,
                (__attribute__((address_space(3))) void*)((char*)&As[buf][0] + (seg << 13) + (wid << 10)),
                16, 0, 0);
        }
    };
    float4 areg[8];
    auto A_ISSUE = [&](int kt) {
        #pragma unroll
        for (int p = 0; p < 8; ++p) {
            int q = p * 512 + tid;
            int row = q >> 4, kq = q & 15;
            areg[p] = *(const float4*)(A32_tile + (size_t)row * KD + kt * 64 + kq * 4);
        }
    };
    auto A_WRITE = [&](int buf) {
        #pragma unroll
        for (int p = 0; p < 8; ++p) {
            int q = p * 512 + tid;
            int row = q >> 4, kq = q & 15;
            ushort4 pk;
            pk.x = f2bf(areg[p].x); pk.y = f2bf(areg[p].y);
            pk.z = f2bf(areg[p].z); pk.w = f2bf(areg[p].w);
            int cc = (kq >> 1) ^ (row & 7);
            *(ushort4*)((char*)&As[buf][0] + row * 128 + (cc << 4) + (kq & 1) * 8) = pk;
        }
    };

    bf16x8_t af[8], bfr[4];
    auto LOADFRAGS = [&](int buf, int ks) {
        #pragma unroll
        for (int i = 0; i < 8; ++i) {
            int row = wm * 128 + i * 16 + lm;
            int cc = (ks * 4 + kb) ^ (row & 7);
            af[i] = *(const bf16x8_t*)((const char*)&As[buf][0] + row * 128 + cc * 16);
        }
        #pragma unroll
        for (int j = 0; j < 4; ++j) {
            int row = wn * 64 + j * 16 + lm;
            int cc = (ks * 4 + kb) ^ (row & 7);
            bfr[j] = *(const bf16x8_t*)((const char*)&Bs[buf][0] + row * 128 + cc * 16);
        }
    };
    auto MFMAC = [&]() {
        __builtin_amdgcn_s_setprio(1);
        #pragma unroll
        for (int i = 0; i < 8; ++i)
            #pragma unroll
            for (int j = 0; j < 4; ++j)
                acc[i][j] = __builtin_amdgcn_mfma_f32_16x16x32_bf16(af[i], bfr[j], acc[i][j], 0, 0, 0);
        __builtin_amdgcn_s_setprio(0);
    };

    if constexpr (AF32) {
        // ---- prologue: publish tile0; A(1)+B(1) in flight (A older) ----
        B_STAGE(0, 0);
        A_ISSUE(0);
        SWAIT_VM0();
        A_WRITE(0);
        A_ISSUE(1);          // queue: A(1)8
        B_STAGE(1, 1);       // queue: A(1)8, B(1)4
        SWAIT_LGKM0();
        SBARRIER();

        int cur = 0;
        #pragma unroll 1
        for (int t = 0; t < NT; ++t) {
            // top invariant: queue = [A(t+1)8, B(t+1)4] when t+1 < NT
            if (t + 1 < NT) {
                SWAIT_VM4();                    // retire A(t+1) (8 oldest)
                A_WRITE(cur ^ 1);               // As[nxt] <- tile t+1 (readers done at t-1 mid-barrier)
                if (t + 2 < NT) A_ISSUE(t + 2); // queue: B(t+1)4, A(t+2)8
            }
            LOADFRAGS(cur, 0);
            MFMAC();                            // overlaps ds_writes + fresh A loads
            LOADFRAGS(cur, 1);
            SWAIT_LGKM0();                      // frag reads + A_WRITE writes drained
            SBARRIER();                         // all waves done reading buf[cur]
            if (t + 2 < NT) B_STAGE(cur, t + 2);   // queue: B(t+1)4, A(t+2)8, B(t+2)4
            MFMAC();                            // overlaps staging
            if (t + 1 < NT) {
                if (t + 2 < NT) { SWAIT_VM12(); }   // retire B(t+1) (4 oldest of 16)
                else            { SWAIT_VM0();  }   // tail: drain B(t+1)
                SBARRIER();                     // publish As/Bs[nxt]
            }
            cur ^= 1;
        }
    } else {
        // ---- WIDE variant (R16-proven): all 24 frags up front, 64-MFMA cluster ----
        bf16x8_t af2[8], bfr2[4];
        auto LOADFRAGS2 = [&](int buf) {
            #pragma unroll
            for (int i = 0; i < 8; ++i) {
                int row = wm * 128 + i * 16 + lm;
                int cc = (4 + kb) ^ (row & 7);
                af2[i] = *(const bf16x8_t*)((const char*)&As[buf][0] + row * 128 + cc * 16);
            }
            #pragma unroll
            for (int j = 0; j < 4; ++j) {
                int row = wn * 64 + j * 16 + lm;
                int cc = (4 + kb) ^ (row & 7);
                bfr2[j] = *(const bf16x8_t*)((const char*)&Bs[buf][0] + row * 128 + cc * 16);
            }
        };
        auto MFMAC2 = [&]() {
            __builtin_amdgcn_s_setprio(1);
            #pragma unroll
            for (int i = 0; i < 8; ++i)
                #pragma unroll
                for (int j = 0; j < 4; ++j)
                    acc[i][j] = __builtin_amdgcn_mfma_f32_16x16x32_bf16(af2[i], bfr2[j], acc[i][j], 0, 0, 0);
            __builtin_amdgcn_s_setprio(0);
        };

        A_STAGE16(0, 0);
        B_STAGE(0, 0);
        __builtin_amdgcn_sched_barrier(0);
        A_STAGE16(1, 1);
        B_STAGE(1, 1);
        SWAIT_VM8();      // tile 0 landed; queue = 8 (tile 1)
        SBARRIER();

        int cur = 0;
        #pragma unroll 1
        for (int t = 0; t < NT; ++t) {
            LOADFRAGS(cur, 0);
            LOADFRAGS2(cur);
            SWAIT_LGKM0();
            SBARRIER();                                   // all waves' reads of buf[cur] retired
            if (t + 2 < NT) { A_STAGE16(cur, t + 2); B_STAGE(cur, t + 2); }   // queue: 8 -> 16
            MFMAC();                                      // 64-MFMA cluster hides in-flight loads
            MFMAC2();
            if (t + 1 < NT) {
                if (t + 2 < NT) { SWAIT_VM8(); }          // retire tile t+1's 8; queue = 8 (t+2)
                else            { SWAIT_VM0(); }          // tail: drain t+1
                SBARRIER();
            }
            cur ^= 1;
        }
    }

    // ---- epilogue ----
    if constexpr (DOCUM) {
        // PASS 1: wave-local causal cumsum (j outer for the carry), results back into acc.
        const int g = lane >> 4;
        const int row0 = bm * GBM + wm * 128;
        #pragma unroll
        for (int j = 0; j < 4; ++j) {
            const int col = bn * GBN + wn * 64 + j * 16 + lm;
            const float bv = bias[col];
            float tot[8], x16[8], x32s[8];
            #pragma unroll
            for (int i = 0; i < 8; ++i) {
                float c0 = acc[i][j][0] + bv;
                float c1 = c0 + acc[i][j][1] + bv;
                float c2 = c1 + acc[i][j][2] + bv;
                float c3 = c2 + acc[i][j][3] + bv;
                acc[i][j][0] = c0; acc[i][j][1] = c1; acc[i][j][2] = c2; acc[i][j][3] = c3;
                tot[i] = c3;
            }
            #pragma unroll
            for (int i = 0; i < 8; ++i) x16[i] = __shfl_xor(tot[i], 16);
            #pragma unroll
            for (int i = 0; i < 8; ++i) x32s[i] = __shfl_xor(tot[i] + x16[i], 32);
            float runbase = 0.f;
            #pragma unroll
            for (int i = 0; i < 8; ++i) {
                float pre = ((g & 1) ? x16[i] : 0.f) + ((g & 2) ? x32s[i] : 0.f);
                float base2 = runbase + pre;
                runbase += tot[i] + x16[i] + x32s[i];
                acc[i][j][0] += base2; acc[i][j][1] += base2;
                acc[i][j][2] += base2; acc[i][j][3] += base2;
            }
            if (g == 0)
                part[((size_t)(row0 >> 7) << 10) + col] = runbase;   // chunk total (f32)
        }
        // PASS 2: store with i-outer/j-inner locality (write-combining friendly, R10-proven).
        #pragma unroll
        for (int i = 0; i < 8; ++i) {
            int row = row0 + i * 16 + g * 4;
            #pragma unroll
            for (int j = 0; j < 4; ++j) {
                int col = bn * GBN + wn * 64 + j * 16 + lm;
                unsigned short* cp = (unsigned short*)Cv + (size_t)row * N + col;
                cp[0]             = f2bf(acc[i][j][0]);
                cp[(size_t)N]     = f2bf(acc[i][j][1]);
                cp[(size_t)2 * N] = f2bf(acc[i][j][2]);
                cp[(size_t)3 * N] = f2bf(acc[i][j][3]);
            }
        }
    } else {
        #pragma unroll
        for (int i = 0; i < 8; ++i) {
            int row = bm * GBM + wm * 128 + i * 16 + (lane >> 4) * 4;
            #pragma unroll
            for (int j = 0; j < 4; ++j) {
                int col = bn * GBN + wn * 64 + j * 16 + lm;
                float bv = bias[col];
                #pragma unroll
                for (int r = 0; r < 4; ++r) {
                    float v = acc[i][j][r] + bv;
                    if constexpr (BF16_OUT)
                        ((unsigned short*)Cv)[(size_t)(row + r) * N + col] = f2bf(v);
                    else
                        ((float*)Cv)[(size_t)(row + r) * N + col] = v;
                }
            }
        }
    }
}

// ---------------- exclusive scan of chunk sums: batch loads -> reg scan -> batch stores ----------------
__global__ __launch_bounds__(256) void chunk_offsets_kernel(float* __restrict__ partQ, float* __restrict__ partK)
{
    int t = blockIdx.x * 256 + threadIdx.x;       // (b,d) flat 0..4095
    float* part = blockIdx.y ? partK : partQ;
    int b = t >> 10, d = t & 1023;
    size_t base = ((size_t)b * NCHUNK) * DMODEL + d;
    float v[NCHUNK];
    #pragma unroll
    for (int c = 0; c < NCHUNK; ++c)               // independent loads, pipelined
        v[c] = part[base + (size_t)c * DMODEL];
    float run = 0.f;
    #pragma unroll
    for (int c = 0; c < NCHUNK; ++c) {             // pure-VALU scan
        float x = v[c];
        v[c] = run;
        run += x;
    }
    #pragma unroll
    for (int c = 0; c < NCHUNK; ++c)               // independent stores
        part[base + (size_t)c * DMODEL] = v[c];
}

// ---------------- MFMA score kernel (sbf padded K=1024: h*64 + z*32 + col) ----------------
__global__ __launch_bounds__(256) void score_kernel(
    const unsigned short* __restrict__ Qc, const unsigned short* __restrict__ Kc,
    const float* __restrict__ partQ, const float* __restrict__ partK,
    const unsigned short* __restrict__ WeP, const unsigned short* __restrict__ WrP,
    float* __restrict__ escore, float* __restrict__ rscore,
    unsigned short* __restrict__ sbf)
{
    __shared__ float n2buf[4][64];
    const int tid = threadIdx.x;
    const int lane = tid & 63;
    const int w = tid >> 6;
    const int lm = lane & 15;
    const int lk = lane >> 4;
    const int c = blockIdx.x;
    const int bh = blockIdx.y;
    const int z = blockIdx.z;
    const int b = bh >> 4, h = bh & 15;
    const unsigned short* X = z ? Kc : Qc;
    const float* part = z ? partK : partQ;
    const unsigned short* WP = z ? WrP : WeP;
    float* eout = z ? rscore : escore;
    const int row0 = c * 256 + w * 64;
    const int co = c * 2 + (w >> 1);

    const float* offp = part + ((size_t)(b * NCHUNK + co)) * DMODEL + h * 64 + lk * 8;
    float o0[8], o1[8];
    {
        float4 a = *(const float4*)(offp);
        float4 bb = *(const float4*)(offp + 4);
        float4 cc = *(const float4*)(offp + 32);
        float4 dd = *(const float4*)(offp + 36);
        o0[0] = a.x; o0[1] = a.y; o0[2] = a.z; o0[3] = a.w;
        o0[4] = bb.x; o0[5] = bb.y; o0[6] = bb.z; o0[7] = bb.w;
        o1[0] = cc.x; o1[1] = cc.y; o1[2] = cc.z; o1[3] = cc.w;
        o1[4] = dd.x; o1[5] = dd.y; o1[6] = dd.z; o1[7] = dd.w;
    }

    const unsigned short* wpb = WP + ((size_t)h << 11) + lm * 64 + lk * 8;
    bf16x8_t b00 = *(const bf16x8_t*)(wpb);
    bf16x8_t b01 = *(const bf16x8_t*)(wpb + 32);
    bf16x8_t b10 = *(const bf16x8_t*)(wpb + 16 * 64);
    bf16x8_t b11 = *(const bf16x8_t*)(wpb + 16 * 64 + 32);

    f32x4_t acc[4][2];
    float n2p[4];
    #pragma unroll
    for (int i = 0; i < 4; ++i) {
        n2p[i] = 0.f;
        acc[i][0] = f32x4_t{0.f, 0.f, 0.f, 0.f};
        acc[i][1] = f32x4_t{0.f, 0.f, 0.f, 0.f};
    }

    const unsigned short* xbase = X + ((size_t)(b * LSEQ + row0 + lm)) * DMODEL + h * 64 + lk * 8;
    #pragma unroll
    for (int i = 0; i < 4; ++i) {
        const unsigned short* xp = xbase + (size_t)(16 * i) * DMODEL;
        bf16x8_t x0 = *(const bf16x8_t*)(xp);
        bf16x8_t x1 = *(const bf16x8_t*)(xp + 32);
        bf16x8_t xa0, xa1;
        #pragma unroll
        for (int j = 0; j < 8; ++j) {
            float xf = b2f((unsigned short)x0[j]) + o0[j];
            n2p[i] = fmaf(xf, xf, n2p[i]);
            xa0[j] = (short)f2bf(xf);
        }
        #pragma unroll
        for (int j = 0; j < 8; ++j) {
            float xf = b2f((unsigned short)x1[j]) + o1[j];
            n2p[i] = fmaf(xf, xf, n2p[i]);
            xa1[j] = (short)f2bf(xf);
        }
        acc[i][0] = __builtin_amdgcn_mfma_f32_16x16x32_bf16(xa0, b00, acc[i][0], 0, 0, 0);
        acc[i][1] = __builtin_amdgcn_mfma_f32_16x16x32_bf16(xa0, b10, acc[i][1], 0, 0, 0);
        acc[i][0] = __builtin_amdgcn_mfma_f32_16x16x32_bf16(xa1, b01, acc[i][0], 0, 0, 0);
        acc[i][1] = __builtin_amdgcn_mfma_f32_16x16x32_bf16(xa1, b11, acc[i][1], 0, 0, 0);
    }

    #pragma unroll
    for (int i = 0; i < 4; ++i) {
        n2p[i] += __shfl_xor(n2p[i], 16);
        n2p[i] += __shfl_xor(n2p[i], 32);
    }
    if (lane < 16) {
        #pragma unroll
        for (int i = 0; i < 4; ++i) n2buf[w][16 * i + lane] = n2p[i];
    }
    __syncthreads();

    #pragma unroll
    for (int i = 0; i < 4; ++i) {
        f32x4_t n2v = *(const f32x4_t*)&n2buf[w][16 * i + lk * 4];
        float inv[4];
        #pragma unroll
        for (int r = 0; r < 4; ++r) {
            int lr = row0 + 16 * i + lk * 4 + r;
            inv[r] = 1.f / fmaxf(sqrtf(n2v[r]), 1e-12f * (float)(lr + 1));
        }
        #pragma unroll
        for (int j = 0; j < 2; ++j) {
            int col = 16 * j + lm;
            #pragma unroll
            for (int r = 0; r < 4; ++r) {
                int lr = row0 + 16 * i + lk * 4 + r;
                float v = acc[i][j][r] * inv[r];
                if (col < RDIM)
                    eout[(((size_t)(b * NHEAD + h)) * LSEQ + lr) * RDIM + col] = v;
                sbf[((size_t)(b * LSEQ + lr)) * 1024 + h * 64 + z * 32 + col] =
                    (col < RDIM) ? f2bf(v) : (unsigned short)0;
            }
        }
    }
}

// ---------------- host launcher ----------------
extern "C" void kernel_launch(void* const* d_in, const int* in_sizes, int n_in,
                              void* d_out, int out_size, void* d_ws, size_t ws_size,
                              hipStream_t stream)
{
    const float* queries = (const float*)d_in[0];
    const float* keys    = (const float*)d_in[1];
    const float* Wq = (const float*)d_in[3];
    const float* bq = (const float*)d_in[4];
    const float* Wk = (const float*)d_in[5];
    const float* bk = (const float*)d_in[6];
    const float* We = (const float*)d_in[7];
    const float* Wr = (const float*)d_in[8];
    const float* Lam = (const float*)d_in[9];
    const float* Wc = (const float*)d_in[10];
    const float* bc = (const float*)d_in[11];
    const float* Wo = (const float*)d_in[12];
    const float* bo = (const float*)d_in[13];

    float* out = (float*)d_out;                        // [B,L,D]
    float* escore = out + (size_t)16777216;            // [B,H,L,R]
    float* rscore = out + (size_t)24641536;            // [B,H,L,R]
    float* lam_out = out + (size_t)32505856;           // [H,R]

    char* ws = (char*)d_ws;
    unsigned short* sbf = (unsigned short*)ws;                    // 32 MiB bf16 scores [16384][1024]
    unsigned short* Qb  = (unsigned short*)(ws + 33554432);       // 32 MiB bf16 [B,L,D] (cumsum'd)
    unsigned short* Kb  = (unsigned short*)(ws + 67108864);       // 32 MiB
    unsigned short* WqT = (unsigned short*)(ws + 100663296);      // 2 MiB
    unsigned short* WkT = (unsigned short*)(ws + 102760448);      // 2 MiB
    unsigned short* WfT = (unsigned short*)(ws + 104857600);      // 2 MiB [1024][1024]
    float* bias2 = (float*)(ws + 106954752);                      // 4 KiB
    float* partQ = (float*)(ws + 106958848);                      // 512 KiB
    float* partK = (float*)(ws + 107483136);                      // 512 KiB
    unsigned short* WeP = (unsigned short*)(ws + 108007424);      // 64 KiB
    unsigned short* WrP = (unsigned short*)(ws + 108072960);      // 64 KiB
    // total ws use: ~103.2 MiB

    dim3 tb(32, 8);
    transpose_cvt_kernel<<<dim3(32, 32, 2), tb, 0, stream>>>(Wq, Wk, WqT, WkT);
    wpack_kernel<<<dim3(16, 2), 256, 0, stream>>>(We, Wr, WeP, WrP);
    bias2_kernel<<<16, 256, 0, stream>>>(Wo, bc, bo, bias2);
    wfold_kernel<<<dim3(16, 16), 256, 0, stream>>>(Wc, Wo, WfT);

    // fused Q+K projections + causal cumsum in epilogue (writes bf16 cumsum + f32 chunk totals)
    gemm8_kernel<true, true, true, 1024><<<dim3(4, 64, 2), 512, 0, stream>>>(
        queries, keys, WqT, WkT, bq, bk, Qb, Kb, partQ, partK, 1024);

    chunk_offsets_kernel<<<dim3(16, 2), 256, 0, stream>>>(partQ, partK);

    score_kernel<<<dim3(16, 64, 2), 256, 0, stream>>>(Qb, Kb, partQ, partK, WeP, WrP,
                                                      escore, rscore, sbf);

    // final GEMM: K=1024 padded (WIDE tile body)
    gemm8_kernel<false, false, false, 1024><<<dim3(4, 64, 1), 512, 0, stream>>>(
        sbf, sbf, WfT, WfT, bias2, bias2, out, out, nullptr, nullptr, 1024);

    hipMemcpyAsync(lam_out, Lam, 480 * sizeof(float), hipMemcpyDeviceToDevice, stream);
}

// Round 18
// 249.485 us; speedup vs baseline: 1.0277x; 1.0277x over previous
//
#include <hip/hip_runtime.h>
#include <hip/hip_bf16.h>

#define BATCH 4
#define LSEQ 4096
#define DMODEL 1024
#define NHEAD 16
#define RDIM 30
#define DKH 64
#define NCHUNK 32
#define CHUNK 128

typedef __attribute__((ext_vector_type(8))) short bf16x8_t;
typedef __attribute__((ext_vector_type(4))) float f32x4_t;

static __device__ __forceinline__ unsigned short f2bf(float f) {
    __hip_bfloat16 h = __float2bfloat16(f);
    unsigned short u;
    __builtin_memcpy(&u, &h, 2);
    return u;
}
static __device__ __forceinline__ float b2f(unsigned short u) {
    unsigned v = ((unsigned)u) << 16;
    float f;
    __builtin_memcpy(&f, &v, 4);
    return f;
}

#define SWAIT_VM8()   { asm volatile("s_waitcnt vmcnt(8)" ::: "memory"); __builtin_amdgcn_sched_barrier(0); }
#define SWAIT_VM4()   { asm volatile("s_waitcnt vmcnt(4)" ::: "memory"); __builtin_amdgcn_sched_barrier(0); }
#define SWAIT_VM0()   { asm volatile("s_waitcnt vmcnt(0)" ::: "memory"); __builtin_amdgcn_sched_barrier(0); }
#define SWAIT_LGKM0() { asm volatile("s_waitcnt lgkmcnt(0)" ::: "memory"); __builtin_amdgcn_sched_barrier(0); }
#define SBARRIER()    { __builtin_amdgcn_s_barrier(); __builtin_amdgcn_sched_barrier(0); }

// ---------------- transpose + convert: W (K,N) f32 -> Wt (N,K) bf16 (z: Wq/Wk) ----------------
__global__ void transpose_cvt_kernel(const float* __restrict__ W0, const float* __restrict__ W1,
                                     unsigned short* __restrict__ O0, unsigned short* __restrict__ O1) {
    __shared__ float tile[32][33];
    const float* W = blockIdx.z ? W1 : W0;
    unsigned short* outT = blockIdx.z ? O1 : O0;
    int n0 = blockIdx.x * 32, k0 = blockIdx.y * 32;
    int tx = threadIdx.x, ty = threadIdx.y;
    #pragma unroll
    for (int r = ty; r < 32; r += 8)
        tile[r][tx] = W[(size_t)(k0 + r) * DMODEL + n0 + tx];
    __syncthreads();
    #pragma unroll
    for (int r = ty; r < 32; r += 8)
        outT[(size_t)(n0 + r) * DMODEL + k0 + tx] = f2bf(tile[tx][r]);
}

// ---------------- wpack: We/Wr [H][64][30] f32 -> WP [H][32 cols][64 k] bf16 ----------------
__global__ void wpack_kernel(const float* __restrict__ We, const float* __restrict__ Wr,
                             unsigned short* __restrict__ WeP, unsigned short* __restrict__ WrP) {
    int h = blockIdx.x;
    const float* W = blockIdx.y ? Wr : We;
    unsigned short* O = blockIdx.y ? WrP : WeP;
    for (int idx = threadIdx.x; idx < 2048; idx += 256) {
        int col = idx >> 6, k = idx & 63;
        float v = (col < RDIM) ? W[((size_t)h * 64 + k) * RDIM + col] : 0.f;
        O[((size_t)h << 11) + idx] = f2bf(v);
    }
}

// ---------------- bias2[n] = bo[n] + sum_d bc[d&63]*Wo[d][n]  (parallel d-groups + LDS reduce) ----------------
__global__ __launch_bounds__(256) void bias2_kernel(
    const float* __restrict__ Wo, const float* __restrict__ bc,
    const float* __restrict__ bo, float* __restrict__ bias2) {
    __shared__ float red[4][64];
    const int n = blockIdx.x * 64 + (threadIdx.x & 63);
    const int dg = threadIdx.x >> 6;              // 0..3, each covers 256 d's
    float a = 0.f;
    #pragma unroll 4
    for (int d = dg * 256; d < dg * 256 + 256; ++d)
        a = fmaf(bc[d & 63], Wo[(size_t)d * DMODEL + n], a);
    red[dg][threadIdx.x & 63] = a;
    __syncthreads();
    if (dg == 0)
        bias2[n] = bo[n] + red[0][threadIdx.x] + red[1][threadIdx.x]
                         + red[2][threadIdx.x] + red[3][threadIdx.x];
}

// ---------------- WfoldT[n][h*64+j] = sum_dk Wc[jr][dk] * Wo[h*64+dk][n]  (bf16, K=1024 padded) ----------------
__global__ __launch_bounds__(256) void wfold_kernel(
    const float* __restrict__ Wc, const float* __restrict__ Wo,
    unsigned short* __restrict__ WfoldT)
{
    __shared__ float WoT[64][65];
    __shared__ float WcT[64][61];
    const int tid = threadIdx.x;
    const int n0 = blockIdx.x * 64, h = blockIdx.y;
    for (int i = tid; i < 4096; i += 256) {
        int dk = i >> 6, n = i & 63;
        WoT[dk][n] = Wo[(size_t)(h * 64 + dk) * DMODEL + n0 + n];
    }
    for (int i = tid; i < 3840; i += 256) {
        int j = i >> 6, dk = i & 63;
        WcT[dk][j] = Wc[j * 64 + dk];
    }
    __syncthreads();
    #pragma unroll 1
    for (int oo = 0; oo < 16; ++oo) {
        int n = (tid >> 6) + oo * 4;
        int j = tid & 63;
        int jr = (j < 30) ? j : (j >= 32 && j < 62) ? (j - 2) : -1;
        float acc = 0.f;
        if (jr >= 0) {
            #pragma unroll
            for (int dk = 0; dk < 64; ++dk)
                acc = fmaf(WcT[dk][jr], WoT[dk][n], acc);
        }
        WfoldT[(size_t)(n0 + n) * 1024 + h * 64 + j] = f2bf(acc);
    }
}

// ================= 256x256 8-wave counted-vmcnt GEMM =================
// AF32 path (QK, R13-proven schedule): A f32 reg-staged + DOCUM cumsum epilogue.
// !AF32 path (final GEMM): WIDE tile body — all 24 fragments read up front,
// single lgkm0 drain + 64-MFMA cluster per K-tile (R16-proven).
#define GBM 256
#define GBN 256

template <bool AF32, bool BF16_OUT, bool DOCUM, int KD>
__global__ __launch_bounds__(512, 2) void gemm8_kernel(
    const void* __restrict__ Av0, const void* __restrict__ Av1,
    const unsigned short* __restrict__ Bt0, const unsigned short* __restrict__ Bt1,
    const float* __restrict__ bias0, const float* __restrict__ bias1,
    void* __restrict__ Cv0, void* __restrict__ Cv1,
    float* __restrict__ part0, float* __restrict__ part1,
    int N)
{
    constexpr int NT = KD / 64;
    __shared__ __align__(16) unsigned short As[2][GBM * 64];
    __shared__ __align__(16) unsigned short Bs[2][GBM * 64];
    const int tid = threadIdx.x;
    const int lane = tid & 63;
    const int wid = tid >> 6;        // 0..7
    const int wm = wid >> 2;         // 0..1
    const int wn = wid & 3;          // 0..3
    const int lm = lane & 15;
    const int kb = lane >> 4;        // 0..3
    const int z = blockIdx.z;

    const void* Av = z ? Av1 : Av0;
    const unsigned short* Bt = z ? Bt1 : Bt0;
    const float* bias = z ? bias1 : bias0;
    void* Cv = z ? Cv1 : Cv0;
    float* part = z ? part1 : part0;

    // bijective XCD chunking per z-slice (nwg = 4*64 = 256, %8 == 0)
    const int nwg = gridDim.x * gridDim.y;
    const int wg = blockIdx.y * gridDim.x + blockIdx.x;
    const int cpx = nwg >> 3;
    const int swz = (wg & 7) * cpx + (wg >> 3);
    const int bn = swz % gridDim.x;
    const int bm = swz / gridDim.x;

    const unsigned short* Btile = Bt + (size_t)(bn * GBN) * KD;
    const float* A32_tile = nullptr;
    const unsigned short* A16_tile = nullptr;
    if constexpr (AF32) A32_tile = (const float*)Av + (size_t)(bm * GBM) * KD;
    else                A16_tile = (const unsigned short*)Av + (size_t)(bm * GBM) * KD;

    f32x4_t acc[8][4];
    #pragma unroll
    for (int i = 0; i < 8; ++i)
        #pragma unroll
        for (int j = 0; j < 4; ++j)
            acc[i][j] = f32x4_t{0.f, 0.f, 0.f, 0.f};

    auto B_STAGE = [&](int buf, int kt) {
        #pragma unroll
        for (int seg = 0; seg < 4; ++seg) {
            const int s = (seg << 13) + (tid << 4);
            const int row = s >> 7;
            const int cc = ((s >> 4) & 7) ^ (row & 7);   // T2 pre-swizzled source, linear dest
            const unsigned short* gb = Btile + (size_t)row * KD + kt * 64 + cc * 8;
            __builtin_amdgcn_global_load_lds(
                (const __attribute__((address_space(1))) void*)gb,
                (__attribute__((address_space(3))) void*)((char*)&Bs[buf][0] + (seg << 13) + (wid << 10)),
                16, 0, 0);
        }
    };
    auto A_STAGE16 = [&](int buf, int kt) {
        #pragma unroll
        for (int seg = 0; seg < 4; ++seg) {
            const int s = (seg << 13) + (tid << 4);
            const int row = s >> 7;
            const int cc = ((s >> 4) & 7) ^ (row & 7);
            const unsigned short* ga = A16_tile + (size_t)row * KD + kt * 64 + cc * 8;
            __builtin_amdgcn_global_load_lds(
                (const __attribute__((address_space(1))) void*)ga,
                (__attribute__((address_space(3))) void*)((char*)&As[buf][0] + (seg << 13) + (wid << 10)),
                16, 0, 0);
        }
    };
    float4 areg[8];
    auto A_ISSUE = [&](int kt) {
        #pragma unroll
        for (int p = 0; p < 8; ++p) {
            int q = p * 512 + tid;
            int row = q >> 4, kq = q & 15;
            areg[p] = *(const float4*)(A32_tile + (size_t)row * KD + kt * 64 + kq * 4);
        }
    };
    auto A_WRITE = [&](int buf) {
        #pragma unroll
        for (int p = 0; p < 8; ++p) {
            int q = p * 512 + tid;
            int row = q >> 4, kq = q & 15;
            ushort4 pk;
            pk.x = f2bf(areg[p].x); pk.y = f2bf(areg[p].y);
            pk.z = f2bf(areg[p].z); pk.w = f2bf(areg[p].w);
            int cc = (kq >> 1) ^ (row & 7);
            *(ushort4*)((char*)&As[buf][0] + row * 128 + (cc << 4) + (kq & 1) * 8) = pk;
        }
    };

    bf16x8_t af[8], bfr[4];
    auto LOADFRAGS = [&](int buf, int ks) {
        #pragma unroll
        for (int i = 0; i < 8; ++i) {
            int row = wm * 128 + i * 16 + lm;
            int cc = (ks * 4 + kb) ^ (row & 7);
            af[i] = *(const bf16x8_t*)((const char*)&As[buf][0] + row * 128 + cc * 16);
        }
        #pragma unroll
        for (int j = 0; j < 4; ++j) {
            int row = wn * 64 + j * 16 + lm;
            int cc = (ks * 4 + kb) ^ (row & 7);
            bfr[j] = *(const bf16x8_t*)((const char*)&Bs[buf][0] + row * 128 + cc * 16);
        }
    };
    auto MFMAC = [&]() {
        __builtin_amdgcn_s_setprio(1);
        #pragma unroll
        for (int i = 0; i < 8; ++i)
            #pragma unroll
            for (int j = 0; j < 4; ++j)
                acc[i][j] = __builtin_amdgcn_mfma_f32_16x16x32_bf16(af[i], bfr[j], acc[i][j], 0, 0, 0);
        __builtin_amdgcn_s_setprio(0);
    };

    if constexpr (AF32) {
        // ---- prologue (R13-proven) ----
        B_STAGE(0, 0);
        A_ISSUE(0);
        SWAIT_VM0();
        A_WRITE(0);
        B_STAGE(1, 1);
        A_ISSUE(1);
        SWAIT_LGKM0();
        SBARRIER();

        int cur = 0;
        #pragma unroll 1
        for (int t = 0; t < NT; ++t) {
            LOADFRAGS(cur, 0);
            MFMAC();
            LOADFRAGS(cur, 1);
            SWAIT_LGKM0();
            SBARRIER();
            if (t + 2 < NT) B_STAGE(cur, t + 2);
            if (t + 1 < NT) {
                if (t + 2 < NT) { SWAIT_VM4(); }
                else            { SWAIT_VM0(); }
                A_WRITE(cur ^ 1);
                if (t + 2 < NT) A_ISSUE(t + 2);
            }
            MFMAC();
            if (t + 1 < NT) { SWAIT_LGKM0(); SBARRIER(); }
            cur ^= 1;
        }
    } else {
        // ---- WIDE variant: second fragment set (named, statically indexed) ----
        bf16x8_t af2[8], bfr2[4];
        auto LOADFRAGS2 = [&](int buf) {
            #pragma unroll
            for (int i = 0; i < 8; ++i) {
                int row = wm * 128 + i * 16 + lm;
                int cc = (4 + kb) ^ (row & 7);
                af2[i] = *(const bf16x8_t*)((const char*)&As[buf][0] + row * 128 + cc * 16);
            }
            #pragma unroll
            for (int j = 0; j < 4; ++j) {
                int row = wn * 64 + j * 16 + lm;
                int cc = (4 + kb) ^ (row & 7);
                bfr2[j] = *(const bf16x8_t*)((const char*)&Bs[buf][0] + row * 128 + cc * 16);
            }
        };
        auto MFMAC2 = [&]() {
            __builtin_amdgcn_s_setprio(1);
            #pragma unroll
            for (int i = 0; i < 8; ++i)
                #pragma unroll
                for (int j = 0; j < 4; ++j)
                    acc[i][j] = __builtin_amdgcn_mfma_f32_16x16x32_bf16(af2[i], bfr2[j], acc[i][j], 0, 0, 0);
            __builtin_amdgcn_s_setprio(0);
        };

        A_STAGE16(0, 0);
        B_STAGE(0, 0);
        __builtin_amdgcn_sched_barrier(0);
        A_STAGE16(1, 1);
        B_STAGE(1, 1);
        SWAIT_VM8();      // tile 0 landed; queue = 8 (tile 1)
        SBARRIER();

        int cur = 0;
        #pragma unroll 1
        for (int t = 0; t < NT; ++t) {
            // read ALL fragments of tile t (24 ds_reads), then free the buffer
            LOADFRAGS(cur, 0);
            LOADFRAGS2(cur);
            SWAIT_LGKM0();
            SBARRIER();                                   // all waves' reads of buf[cur] retired
            if (t + 2 < NT) { A_STAGE16(cur, t + 2); B_STAGE(cur, t + 2); }   // queue: 8 -> 16
            MFMAC();                                      // 64-MFMA cluster hides in-flight loads
            MFMAC2();
            if (t + 1 < NT) {
                if (t + 2 < NT) { SWAIT_VM8(); }          // retire tile t+1's 8; queue = 8 (t+2)
                else            { SWAIT_VM0(); }          // tail: drain t+1
                SBARRIER();
            }
            cur ^= 1;
        }
    }

    // ---- epilogue ----
    if constexpr (DOCUM) {
        // PASS 1: wave-local causal cumsum (j outer for the carry), results back into acc.
        const int g = lane >> 4;
        const int row0 = bm * GBM + wm * 128;
        #pragma unroll
        for (int j = 0; j < 4; ++j) {
            const int col = bn * GBN + wn * 64 + j * 16 + lm;
            const float bv = bias[col];
            float tot[8], x16[8], x32s[8];
            #pragma unroll
            for (int i = 0; i < 8; ++i) {
                float c0 = acc[i][j][0] + bv;
                float c1 = c0 + acc[i][j][1] + bv;
                float c2 = c1 + acc[i][j][2] + bv;
                float c3 = c2 + acc[i][j][3] + bv;
                acc[i][j][0] = c0; acc[i][j][1] = c1; acc[i][j][2] = c2; acc[i][j][3] = c3;
                tot[i] = c3;
            }
            #pragma unroll
            for (int i = 0; i < 8; ++i) x16[i] = __shfl_xor(tot[i], 16);
            #pragma unroll
            for (int i = 0; i < 8; ++i) x32s[i] = __shfl_xor(tot[i] + x16[i], 32);
            float runbase = 0.f;
            #pragma unroll
            for (int i = 0; i < 8; ++i) {
                float pre = ((g & 1) ? x16[i] : 0.f) + ((g & 2) ? x32s[i] : 0.f);
                float base2 = runbase + pre;
                runbase += tot[i] + x16[i] + x32s[i];
                acc[i][j][0] += base2; acc[i][j][1] += base2;
                acc[i][j][2] += base2; acc[i][j][3] += base2;
            }
            if (g == 0)
                part[((size_t)(row0 >> 7) << 10) + col] = runbase;   // chunk total (f32)
        }
        // PASS 2: store with i-outer/j-inner locality (write-combining friendly, R10-proven).
        #pragma unroll
        for (int i = 0; i < 8; ++i) {
            int row = row0 + i * 16 + g * 4;
            #pragma unroll
            for (int j = 0; j < 4; ++j) {
                int col = bn * GBN + wn * 64 + j * 16 + lm;
                unsigned short* cp = (unsigned short*)Cv + (size_t)row * N + col;
                cp[0]             = f2bf(acc[i][j][0]);
                cp[(size_t)N]     = f2bf(acc[i][j][1]);
                cp[(size_t)2 * N] = f2bf(acc[i][j][2]);
                cp[(size_t)3 * N] = f2bf(acc[i][j][3]);
            }
        }
    } else {
        #pragma unroll
        for (int i = 0; i < 8; ++i) {
            int row = bm * GBM + wm * 128 + i * 16 + (lane >> 4) * 4;
            #pragma unroll
            for (int j = 0; j < 4; ++j) {
                int col = bn * GBN + wn * 64 + j * 16 + lm;
                float bv = bias[col];
                #pragma unroll
                for (int r = 0; r < 4; ++r) {
                    float v = acc[i][j][r] + bv;
                    if constexpr (BF16_OUT)
                        ((unsigned short*)Cv)[(size_t)(row + r) * N + col] = f2bf(v);
                    else
                        ((float*)Cv)[(size_t)(row + r) * N + col] = v;
                }
            }
        }
    }
}

// ---------------- exclusive scan of chunk sums: batch loads -> reg scan -> batch stores ----------------
__global__ __launch_bounds__(256) void chunk_offsets_kernel(float* __restrict__ partQ, float* __restrict__ partK)
{
    int t = blockIdx.x * 256 + threadIdx.x;       // (b,d) flat 0..4095
    float* part = blockIdx.y ? partK : partQ;
    int b = t >> 10, d = t & 1023;
    size_t base = ((size_t)b * NCHUNK) * DMODEL + d;
    float v[NCHUNK];
    #pragma unroll
    for (int c = 0; c < NCHUNK; ++c)               // independent loads, pipelined
        v[c] = part[base + (size_t)c * DMODEL];
    float run = 0.f;
    #pragma unroll
    for (int c = 0; c < NCHUNK; ++c) {             // pure-VALU scan
        float x = v[c];
        v[c] = run;
        run += x;
    }
    #pragma unroll
    for (int c = 0; c < NCHUNK; ++c)               // independent stores
        part[base + (size_t)c * DMODEL] = v[c];
}

// ---------------- MFMA score kernel (sbf padded K=1024: h*64 + z*32 + col) ----------------
__global__ __launch_bounds__(256) void score_kernel(
    const unsigned short* __restrict__ Qc, const unsigned short* __restrict__ Kc,
    const float* __restrict__ partQ, const float* __restrict__ partK,
    const unsigned short* __restrict__ WeP, const unsigned short* __restrict__ WrP,
    float* __restrict__ escore, float* __restrict__ rscore,
    unsigned short* __restrict__ sbf)
{
    __shared__ float n2buf[4][64];
    const int tid = threadIdx.x;
    const int lane = tid & 63;
    const int w = tid >> 6;
    const int lm = lane & 15;
    const int lk = lane >> 4;
    const int c = blockIdx.x;
    const int bh = blockIdx.y;
    const int z = blockIdx.z;
    const int b = bh >> 4, h = bh & 15;
    const unsigned short* X = z ? Kc : Qc;
    const float* part = z ? partK : partQ;
    const unsigned short* WP = z ? WrP : WeP;
    float* eout = z ? rscore : escore;
    const int row0 = c * 256 + w * 64;
    const int co = c * 2 + (w >> 1);

    const float* offp = part + ((size_t)(b * NCHUNK + co)) * DMODEL + h * 64 + lk * 8;
    float o0[8], o1[8];
    {
        float4 a = *(const float4*)(offp);
        float4 bb = *(const float4*)(offp + 4);
        float4 cc = *(const float4*)(offp + 32);
        float4 dd = *(const float4*)(offp + 36);
        o0[0] = a.x; o0[1] = a.y; o0[2] = a.z; o0[3] = a.w;
        o0[4] = bb.x; o0[5] = bb.y; o0[6] = bb.z; o0[7] = bb.w;
        o1[0] = cc.x; o1[1] = cc.y; o1[2] = cc.z; o1[3] = cc.w;
        o1[4] = dd.x; o1[5] = dd.y; o1[6] = dd.z; o1[7] = dd.w;
    }

    const unsigned short* wpb = WP + ((size_t)h << 11) + lm * 64 + lk * 8;
    bf16x8_t b00 = *(const bf16x8_t*)(wpb);
    bf16x8_t b01 = *(const bf16x8_t*)(wpb + 32);
    bf16x8_t b10 = *(const bf16x8_t*)(wpb + 16 * 64);
    bf16x8_t b11 = *(const bf16x8_t*)(wpb + 16 * 64 + 32);

    f32x4_t acc[4][2];
    float n2p[4];
    #pragma unroll
    for (int i = 0; i < 4; ++i) {
        n2p[i] = 0.f;
        acc[i][0] = f32x4_t{0.f, 0.f, 0.f, 0.f};
        acc[i][1] = f32x4_t{0.f, 0.f, 0.f, 0.f};
    }

    const unsigned short* xbase = X + ((size_t)(b * LSEQ + row0 + lm)) * DMODEL + h * 64 + lk * 8;
    #pragma unroll
    for (int i = 0; i < 4; ++i) {
        const unsigned short* xp = xbase + (size_t)(16 * i) * DMODEL;
        bf16x8_t x0 = *(const bf16x8_t*)(xp);
        bf16x8_t x1 = *(const bf16x8_t*)(xp + 32);
        bf16x8_t xa0, xa1;
        #pragma unroll
        for (int j = 0; j < 8; ++j) {
            float xf = b2f((unsigned short)x0[j]) + o0[j];
            n2p[i] = fmaf(xf, xf, n2p[i]);
            xa0[j] = (short)f2bf(xf);
        }
        #pragma unroll
        for (int j = 0; j < 8; ++j) {
            float xf = b2f((unsigned short)x1[j]) + o1[j];
            n2p[i] = fmaf(xf, xf, n2p[i]);
            xa1[j] = (short)f2bf(xf);
        }
        acc[i][0] = __builtin_amdgcn_mfma_f32_16x16x32_bf16(xa0, b00, acc[i][0], 0, 0, 0);
        acc[i][1] = __builtin_amdgcn_mfma_f32_16x16x32_bf16(xa0, b10, acc[i][1], 0, 0, 0);
        acc[i][0] = __builtin_amdgcn_mfma_f32_16x16x32_bf16(xa1, b01, acc[i][0], 0, 0, 0);
        acc[i][1] = __builtin_amdgcn_mfma_f32_16x16x32_bf16(xa1, b11, acc[i][1], 0, 0, 0);
    }

    #pragma unroll
    for (int i = 0; i < 4; ++i) {
        n2p[i] += __shfl_xor(n2p[i], 16);
        n2p[i] += __shfl_xor(n2p[i], 32);
    }
    if (lane < 16) {
        #pragma unroll
        for (int i = 0; i < 4; ++i) n2buf[w][16 * i + lane] = n2p[i];
    }
    __syncthreads();

    #pragma unroll
    for (int i = 0; i < 4; ++i) {
        f32x4_t n2v = *(const f32x4_t*)&n2buf[w][16 * i + lk * 4];
        float inv[4];
        #pragma unroll
        for (int r = 0; r < 4; ++r) {
            int lr = row0 + 16 * i + lk * 4 + r;
            inv[r] = 1.f / fmaxf(sqrtf(n2v[r]), 1e-12f * (float)(lr + 1));
        }
        #pragma unroll
        for (int j = 0; j < 2; ++j) {
            int col = 16 * j + lm;
            #pragma unroll
            for (int r = 0; r < 4; ++r) {
                int lr = row0 + 16 * i + lk * 4 + r;
                float v = acc[i][j][r] * inv[r];
                if (col < RDIM)
                    eout[(((size_t)(b * NHEAD + h)) * LSEQ + lr) * RDIM + col] = v;
                sbf[((size_t)(b * LSEQ + lr)) * 1024 + h * 64 + z * 32 + col] =
                    (col < RDIM) ? f2bf(v) : (unsigned short)0;
            }
        }
    }
}

// ---------------- host launcher ----------------
extern "C" void kernel_launch(void* const* d_in, const int* in_sizes, int n_in,
                              void* d_out, int out_size, void* d_ws, size_t ws_size,
                              hipStream_t stream)
{
    const float* queries = (const float*)d_in[0];
    const float* keys    = (const float*)d_in[1];
    const float* Wq = (const float*)d_in[3];
    const float* bq = (const float*)d_in[4];
    const float* Wk = (const float*)d_in[5];
    const float* bk = (const float*)d_in[6];
    const float* We = (const float*)d_in[7];
    const float* Wr = (const float*)d_in[8];
    const float* Lam = (const float*)d_in[9];
    const float* Wc = (const float*)d_in[10];
    const float* bc = (const float*)d_in[11];
    const float* Wo = (const float*)d_in[12];
    const float* bo = (const float*)d_in[13];

    float* out = (float*)d_out;                        // [B,L,D]
    float* escore = out + (size_t)16777216;            // [B,H,L,R]
    float* rscore = out + (size_t)24641536;            // [B,H,L,R]
    float* lam_out = out + (size_t)32505856;           // [H,R]

    char* ws = (char*)d_ws;
    unsigned short* sbf = (unsigned short*)ws;                    // 32 MiB bf16 scores [16384][1024]
    unsigned short* Qb  = (unsigned short*)(ws + 33554432);       // 32 MiB bf16 [B,L,D] (cumsum'd)
    unsigned short* Kb  = (unsigned short*)(ws + 67108864);       // 32 MiB
    unsigned short* WqT = (unsigned short*)(ws + 100663296);      // 2 MiB
    unsigned short* WkT = (unsigned short*)(ws + 102760448);      // 2 MiB
    unsigned short* WfT = (unsigned short*)(ws + 104857600);      // 2 MiB [1024][1024]
    float* bias2 = (float*)(ws + 106954752);                      // 4 KiB
    float* partQ = (float*)(ws + 106958848);                      // 512 KiB
    float* partK = (float*)(ws + 107483136);                      // 512 KiB
    unsigned short* WeP = (unsigned short*)(ws + 108007424);      // 64 KiB
    unsigned short* WrP = (unsigned short*)(ws + 108072960);      // 64 KiB
    // total ws use: ~103.2 MiB

    dim3 tb(32, 8);
    transpose_cvt_kernel<<<dim3(32, 32, 2), tb, 0, stream>>>(Wq, Wk, WqT, WkT);
    wpack_kernel<<<dim3(16, 2), 256, 0, stream>>>(We, Wr, WeP, WrP);
    bias2_kernel<<<16, 256, 0, stream>>>(Wo, bc, bo, bias2);
    wfold_kernel<<<dim3(16, 16), 256, 0, stream>>>(Wc, Wo, WfT);

    // fused Q+K projections + causal cumsum in epilogue (writes bf16 cumsum + f32 chunk totals)
    gemm8_kernel<true, true, true, 1024><<<dim3(4, 64, 2), 512, 0, stream>>>(
        queries, keys, WqT, WkT, bq, bk, Qb, Kb, partQ, partK, 1024);

    chunk_offsets_kernel<<<dim3(16, 2), 256, 0, stream>>>(partQ, partK);

    score_kernel<<<dim3(16, 64, 2), 256, 0, stream>>>(Qb, Kb, partQ, partK, WeP, WrP,
                                                      escore, rscore, sbf);

    // final GEMM: K=1024 padded (WIDE tile body)
    gemm8_kernel<false, false, false, 1024><<<dim3(4, 64, 1), 512, 0, stream>>>(
        sbf, sbf, WfT, WfT, bias2, bias2, out, out, nullptr, nullptr, 1024);

    hipMemcpyAsync(lam_out, Lam, 480 * sizeof(float), hipMemcpyDeviceToDevice, stream);
}

// Round 19
// 246.368 us; speedup vs baseline: 1.0407x; 1.0127x over previous
//
#include <hip/hip_runtime.h>
#include <hip/hip_bf16.h>

#define BATCH 4
#define LSEQ 4096
#define DMODEL 1024
#define NHEAD 16
#define RDIM 30
#define DKH 64
#define NCHUNK 32
#define CHUNK 128

typedef __attribute__((ext_vector_type(8))) short bf16x8_t;
typedef __attribute__((ext_vector_type(4))) float f32x4_t;

static __device__ __forceinline__ unsigned short f2bf(float f) {
    __hip_bfloat16 h = __float2bfloat16(f);
    unsigned short u;
    __builtin_memcpy(&u, &h, 2);
    return u;
}
static __device__ __forceinline__ float b2f(unsigned short u) {
    unsigned v = ((unsigned)u) << 16;
    float f;
    __builtin_memcpy(&f, &v, 4);
    return f;
}

#define SWAIT_VM8()   { asm volatile("s_waitcnt vmcnt(8)" ::: "memory"); __builtin_amdgcn_sched_barrier(0); }
#define SWAIT_VM4()   { asm volatile("s_waitcnt vmcnt(4)" ::: "memory"); __builtin_amdgcn_sched_barrier(0); }
#define SWAIT_VM0()   { asm volatile("s_waitcnt vmcnt(0)" ::: "memory"); __builtin_amdgcn_sched_barrier(0); }
#define SWAIT_LGKM0() { asm volatile("s_waitcnt lgkmcnt(0)" ::: "memory"); __builtin_amdgcn_sched_barrier(0); }
#define SBARRIER()    { __builtin_amdgcn_s_barrier(); __builtin_amdgcn_sched_barrier(0); }

// ---------------- transpose + convert: W (K,N) f32 -> Wt (N,K) bf16 (z: Wq/Wk) ----------------
__global__ void transpose_cvt_kernel(const float* __restrict__ W0, const float* __restrict__ W1,
                                     unsigned short* __restrict__ O0, unsigned short* __restrict__ O1) {
    __shared__ float tile[32][33];
    const float* W = blockIdx.z ? W1 : W0;
    unsigned short* outT = blockIdx.z ? O1 : O0;
    int n0 = blockIdx.x * 32, k0 = blockIdx.y * 32;
    int tx = threadIdx.x, ty = threadIdx.y;
    #pragma unroll
    for (int r = ty; r < 32; r += 8)
        tile[r][tx] = W[(size_t)(k0 + r) * DMODEL + n0 + tx];
    __syncthreads();
    #pragma unroll
    for (int r = ty; r < 32; r += 8)
        outT[(size_t)(n0 + r) * DMODEL + k0 + tx] = f2bf(tile[tx][r]);
}

// ---------------- wpack: We/Wr [H][64][30] f32 -> WP [H][32 cols][64 k] bf16 ----------------
__global__ void wpack_kernel(const float* __restrict__ We, const float* __restrict__ Wr,
                             unsigned short* __restrict__ WeP, unsigned short* __restrict__ WrP) {
    int h = blockIdx.x;
    const float* W = blockIdx.y ? Wr : We;
    unsigned short* O = blockIdx.y ? WrP : WeP;
    for (int idx = threadIdx.x; idx < 2048; idx += 256) {
        int col = idx >> 6, k = idx & 63;
        float v = (col < RDIM) ? W[((size_t)h * 64 + k) * RDIM + col] : 0.f;
        O[((size_t)h << 11) + idx] = f2bf(v);
    }
}

// ---------------- bias2[n] = bo[n] + sum_d bc[d&63]*Wo[d][n]  (parallel d-groups + LDS reduce) ----------------
__global__ __launch_bounds__(256) void bias2_kernel(
    const float* __restrict__ Wo, const float* __restrict__ bc,
    const float* __restrict__ bo, float* __restrict__ bias2) {
    __shared__ float red[4][64];
    const int n = blockIdx.x * 64 + (threadIdx.x & 63);
    const int dg = threadIdx.x >> 6;              // 0..3, each covers 256 d's
    float a = 0.f;
    #pragma unroll 4
    for (int d = dg * 256; d < dg * 256 + 256; ++d)
        a = fmaf(bc[d & 63], Wo[(size_t)d * DMODEL + n], a);
    red[dg][threadIdx.x & 63] = a;
    __syncthreads();
    if (dg == 0)
        bias2[n] = bo[n] + red[0][threadIdx.x] + red[1][threadIdx.x]
                         + red[2][threadIdx.x] + red[3][threadIdx.x];
}

// ---------------- WfoldT[n][h*64+j] = sum_dk Wc[jr][dk] * Wo[h*64+dk][n]  (bf16, K=1024 padded) ----------------
__global__ __launch_bounds__(256) void wfold_kernel(
    const float* __restrict__ Wc, const float* __restrict__ Wo,
    unsigned short* __restrict__ WfoldT)
{
    __shared__ float WoT[64][65];
    __shared__ float WcT[64][61];
    const int tid = threadIdx.x;
    const int n0 = blockIdx.x * 64, h = blockIdx.y;
    for (int i = tid; i < 4096; i += 256) {
        int dk = i >> 6, n = i & 63;
        WoT[dk][n] = Wo[(size_t)(h * 64 + dk) * DMODEL + n0 + n];
    }
    for (int i = tid; i < 3840; i += 256) {
        int j = i >> 6, dk = i & 63;
        WcT[dk][j] = Wc[j * 64 + dk];
    }
    __syncthreads();
    #pragma unroll 1
    for (int oo = 0; oo < 16; ++oo) {
        int n = (tid >> 6) + oo * 4;
        int j = tid & 63;
        int jr = (j < 30) ? j : (j >= 32 && j < 62) ? (j - 2) : -1;
        float acc = 0.f;
        if (jr >= 0) {
            #pragma unroll
            for (int dk = 0; dk < 64; ++dk)
                acc = fmaf(WcT[dk][jr], WoT[dk][n], acc);
        }
        WfoldT[(size_t)(n0 + n) * 1024 + h * 64 + j] = f2bf(acc);
    }
}

// ================= 256x256 8-wave counted-vmcnt GEMM =================
// AF32 path (QK): R13 schedule + forced-rolled loop (the actual R16 win).
// !AF32 path (final GEMM): same R13 2-half schedule + forced-rolled loop
// (WIDE body reverted — it was per-generation slower).
#define GBM 256
#define GBN 256

template <bool AF32, bool BF16_OUT, bool DOCUM, int KD>
__global__ __launch_bounds__(512, 2) void gemm8_kernel(
    const void* __restrict__ Av0, const void* __restrict__ Av1,
    const unsigned short* __restrict__ Bt0, const unsigned short* __restrict__ Bt1,
    const float* __restrict__ bias0, const float* __restrict__ bias1,
    void* __restrict__ Cv0, void* __restrict__ Cv1,
    float* __restrict__ part0, float* __restrict__ part1,
    int N)
{
    constexpr int NT = KD / 64;
    __shared__ __align__(16) unsigned short As[2][GBM * 64];
    __shared__ __align__(16) unsigned short Bs[2][GBM * 64];
    const int tid = threadIdx.x;
    const int lane = tid & 63;
    const int wid = tid >> 6;        // 0..7
    const int wm = wid >> 2;         // 0..1
    const int wn = wid & 3;          // 0..3
    const int lm = lane & 15;
    const int kb = lane >> 4;        // 0..3
    const int z = blockIdx.z;

    const void* Av = z ? Av1 : Av0;
    const unsigned short* Bt = z ? Bt1 : Bt0;
    const float* bias = z ? bias1 : bias0;
    void* Cv = z ? Cv1 : Cv0;
    float* part = z ? part1 : part0;

    // bijective XCD chunking per z-slice (nwg = 4*64 = 256, %8 == 0)
    const int nwg = gridDim.x * gridDim.y;
    const int wg = blockIdx.y * gridDim.x + blockIdx.x;
    const int cpx = nwg >> 3;
    const int swz = (wg & 7) * cpx + (wg >> 3);
    const int bn = swz % gridDim.x;
    const int bm = swz / gridDim.x;

    const unsigned short* Btile = Bt + (size_t)(bn * GBN) * KD;
    const float* A32_tile = nullptr;
    const unsigned short* A16_tile = nullptr;
    if constexpr (AF32) A32_tile = (const float*)Av + (size_t)(bm * GBM) * KD;
    else                A16_tile = (const unsigned short*)Av + (size_t)(bm * GBM) * KD;

    f32x4_t acc[8][4];
    #pragma unroll
    for (int i = 0; i < 8; ++i)
        #pragma unroll
        for (int j = 0; j < 4; ++j)
            acc[i][j] = f32x4_t{0.f, 0.f, 0.f, 0.f};

    auto B_STAGE = [&](int buf, int kt) {
        #pragma unroll
        for (int seg = 0; seg < 4; ++seg) {
            const int s = (seg << 13) + (tid << 4);
            const int row = s >> 7;
            const int cc = ((s >> 4) & 7) ^ (row & 7);   // T2 pre-swizzled source, linear dest
            const unsigned short* gb = Btile + (size_t)row * KD + kt * 64 + cc * 8;
            __builtin_amdgcn_global_load_lds(
                (const __attribute__((address_space(1))) void*)gb,
                (__attribute__((address_space(3))) void*)((char*)&Bs[buf][0] + (seg << 13) + (wid << 10)),
                16, 0, 0);
        }
    };
    auto A_STAGE16 = [&](int buf, int kt) {
        #pragma unroll
        for (int seg = 0; seg < 4; ++seg) {
            const int s = (seg << 13) + (tid << 4);
            const int row = s >> 7;
            const int cc = ((s >> 4) & 7) ^ (row & 7);
            const unsigned short* ga = A16_tile + (size_t)row * KD + kt * 64 + cc * 8;
            __builtin_amdgcn_global_load_lds(
                (const __attribute__((address_space(1))) void*)ga,
                (__attribute__((address_space(3))) void*)((char*)&As[buf][0] + (seg << 13) + (wid << 10)),
                16, 0, 0);
        }
    };
    float4 areg[8];
    auto A_ISSUE = [&](int kt) {
        #pragma unroll
        for (int p = 0; p < 8; ++p) {
            int q = p * 512 + tid;
            int row = q >> 4, kq = q & 15;
            areg[p] = *(const float4*)(A32_tile + (size_t)row * KD + kt * 64 + kq * 4);
        }
    };
    auto A_WRITE = [&](int buf) {
        #pragma unroll
        for (int p = 0; p < 8; ++p) {
            int q = p * 512 + tid;
            int row = q >> 4, kq = q & 15;
            ushort4 pk;
            pk.x = f2bf(areg[p].x); pk.y = f2bf(areg[p].y);
            pk.z = f2bf(areg[p].z); pk.w = f2bf(areg[p].w);
            int cc = (kq >> 1) ^ (row & 7);
            *(ushort4*)((char*)&As[buf][0] + row * 128 + (cc << 4) + (kq & 1) * 8) = pk;
        }
    };

    bf16x8_t af[8], bfr[4];
    auto LOADFRAGS = [&](int buf, int ks) {
        #pragma unroll
        for (int i = 0; i < 8; ++i) {
            int row = wm * 128 + i * 16 + lm;
            int cc = (ks * 4 + kb) ^ (row & 7);
            af[i] = *(const bf16x8_t*)((const char*)&As[buf][0] + row * 128 + cc * 16);
        }
        #pragma unroll
        for (int j = 0; j < 4; ++j) {
            int row = wn * 64 + j * 16 + lm;
            int cc = (ks * 4 + kb) ^ (row & 7);
            bfr[j] = *(const bf16x8_t*)((const char*)&Bs[buf][0] + row * 128 + cc * 16);
        }
    };
    auto MFMAC = [&]() {
        __builtin_amdgcn_s_setprio(1);
        #pragma unroll
        for (int i = 0; i < 8; ++i)
            #pragma unroll
            for (int j = 0; j < 4; ++j)
                acc[i][j] = __builtin_amdgcn_mfma_f32_16x16x32_bf16(af[i], bfr[j], acc[i][j], 0, 0, 0);
        __builtin_amdgcn_s_setprio(0);
    };

    if constexpr (AF32) {
        // ---- prologue (R13-proven) ----
        B_STAGE(0, 0);
        A_ISSUE(0);
        SWAIT_VM0();
        A_WRITE(0);
        B_STAGE(1, 1);
        A_ISSUE(1);
        SWAIT_LGKM0();
        SBARRIER();

        int cur = 0;
        #pragma unroll 1
        for (int t = 0; t < NT; ++t) {
            LOADFRAGS(cur, 0);
            MFMAC();
            LOADFRAGS(cur, 1);
            SWAIT_LGKM0();
            SBARRIER();
            if (t + 2 < NT) B_STAGE(cur, t + 2);
            if (t + 1 < NT) {
                if (t + 2 < NT) { SWAIT_VM4(); }
                else            { SWAIT_VM0(); }
                A_WRITE(cur ^ 1);
                if (t + 2 < NT) A_ISSUE(t + 2);
            }
            MFMAC();
            if (t + 1 < NT) { SWAIT_LGKM0(); SBARRIER(); }
            cur ^= 1;
        }
    } else {
        // ---- R13 2-half schedule, forced-rolled loop ----
        A_STAGE16(0, 0);
        B_STAGE(0, 0);
        __builtin_amdgcn_sched_barrier(0);
        A_STAGE16(1, 1);
        B_STAGE(1, 1);
        SWAIT_VM8();      // tile 0 landed; queue = 8 (tile 1)
        SBARRIER();

        int cur = 0;
        #pragma unroll 1
        for (int t = 0; t < NT; ++t) {
            LOADFRAGS(cur, 0);
            MFMAC();
            LOADFRAGS(cur, 1);
            SWAIT_LGKM0();
            SBARRIER();                                   // all waves' reads of buf[cur] retired
            if (t + 2 < NT) { A_STAGE16(cur, t + 2); B_STAGE(cur, t + 2); }   // queue: 8 -> 16
            MFMAC();                                      // overlaps staging
            if (t + 1 < NT) {
                if (t + 2 < NT) { SWAIT_VM8(); }          // retire tile t+1's 8; queue = 8 (t+2)
                else            { SWAIT_VM0(); }          // tail: drain t+1
                SBARRIER();
            }
            cur ^= 1;
        }
    }

    // ---- epilogue ----
    if constexpr (DOCUM) {
        // PASS 1: wave-local causal cumsum (j outer for the carry), results back into acc.
        const int g = lane >> 4;
        const int row0 = bm * GBM + wm * 128;
        #pragma unroll
        for (int j = 0; j < 4; ++j) {
            const int col = bn * GBN + wn * 64 + j * 16 + lm;
            const float bv = bias[col];
            float tot[8], x16[8], x32s[8];
            #pragma unroll
            for (int i = 0; i < 8; ++i) {
                float c0 = acc[i][j][0] + bv;
                float c1 = c0 + acc[i][j][1] + bv;
                float c2 = c1 + acc[i][j][2] + bv;
                float c3 = c2 + acc[i][j][3] + bv;
                acc[i][j][0] = c0; acc[i][j][1] = c1; acc[i][j][2] = c2; acc[i][j][3] = c3;
                tot[i] = c3;
            }
            #pragma unroll
            for (int i = 0; i < 8; ++i) x16[i] = __shfl_xor(tot[i], 16);
            #pragma unroll
            for (int i = 0; i < 8; ++i) x32s[i] = __shfl_xor(tot[i] + x16[i], 32);
            float runbase = 0.f;
            #pragma unroll
            for (int i = 0; i < 8; ++i) {
                float pre = ((g & 1) ? x16[i] : 0.f) + ((g & 2) ? x32s[i] : 0.f);
                float base2 = runbase + pre;
                runbase += tot[i] + x16[i] + x32s[i];
                acc[i][j][0] += base2; acc[i][j][1] += base2;
                acc[i][j][2] += base2; acc[i][j][3] += base2;
            }
            if (g == 0)
                part[((size_t)(row0 >> 7) << 10) + col] = runbase;   // chunk total (f32)
        }
        // PASS 2: store with i-outer/j-inner locality (write-combining friendly, R10-proven).
        #pragma unroll
        for (int i = 0; i < 8; ++i) {
            int row = row0 + i * 16 + g * 4;
            #pragma unroll
            for (int j = 0; j < 4; ++j) {
                int col = bn * GBN + wn * 64 + j * 16 + lm;
                unsigned short* cp = (unsigned short*)Cv + (size_t)row * N + col;
                cp[0]             = f2bf(acc[i][j][0]);
                cp[(size_t)N]     = f2bf(acc[i][j][1]);
                cp[(size_t)2 * N] = f2bf(acc[i][j][2]);
                cp[(size_t)3 * N] = f2bf(acc[i][j][3]);
            }
        }
    } else {
        #pragma unroll
        for (int i = 0; i < 8; ++i) {
            int row = bm * GBM + wm * 128 + i * 16 + (lane >> 4) * 4;
            #pragma unroll
            for (int j = 0; j < 4; ++j) {
                int col = bn * GBN + wn * 64 + j * 16 + lm;
                float bv = bias[col];
                #pragma unroll
                for (int r = 0; r < 4; ++r) {
                    float v = acc[i][j][r] + bv;
                    if constexpr (BF16_OUT)
                        ((unsigned short*)Cv)[(size_t)(row + r) * N + col] = f2bf(v);
                    else
                        ((float*)Cv)[(size_t)(row + r) * N + col] = v;
                }
            }
        }
    }
}

// ---------------- exclusive scan of chunk sums: batch loads -> reg scan -> batch stores ----------------
__global__ __launch_bounds__(256) void chunk_offsets_kernel(float* __restrict__ partQ, float* __restrict__ partK)
{
    int t = blockIdx.x * 256 + threadIdx.x;       // (b,d) flat 0..4095
    float* part = blockIdx.y ? partK : partQ;
    int b = t >> 10, d = t & 1023;
    size_t base = ((size_t)b * NCHUNK) * DMODEL + d;
    float v[NCHUNK];
    #pragma unroll
    for (int c = 0; c < NCHUNK; ++c)               // independent loads, pipelined
        v[c] = part[base + (size_t)c * DMODEL];
    float run = 0.f;
    #pragma unroll
    for (int c = 0; c < NCHUNK; ++c) {             // pure-VALU scan
        float x = v[c];
        v[c] = run;
        run += x;
    }
    #pragma unroll
    for (int c = 0; c < NCHUNK; ++c)               // independent stores
        part[base + (size_t)c * DMODEL] = v[c];
}

// ---------------- MFMA score kernel (sbf padded K=1024: h*64 + z*32 + col) ----------------
__global__ __launch_bounds__(256) void score_kernel(
    const unsigned short* __restrict__ Qc, const unsigned short* __restrict__ Kc,
    const float* __restrict__ partQ, const float* __restrict__ partK,
    const unsigned short* __restrict__ WeP, const unsigned short* __restrict__ WrP,
    float* __restrict__ escore, float* __restrict__ rscore,
    unsigned short* __restrict__ sbf)
{
    __shared__ float n2buf[4][64];
    const int tid = threadIdx.x;
    const int lane = tid & 63;
    const int w = tid >> 6;
    const int lm = lane & 15;
    const int lk = lane >> 4;
    const int c = blockIdx.x;
    const int bh = blockIdx.y;
    const int z = blockIdx.z;
    const int b = bh >> 4, h = bh & 15;
    const unsigned short* X = z ? Kc : Qc;
    const float* part = z ? partK : partQ;
    const unsigned short* WP = z ? WrP : WeP;
    float* eout = z ? rscore : escore;
    const int row0 = c * 256 + w * 64;
    const int co = c * 2 + (w >> 1);

    const float* offp = part + ((size_t)(b * NCHUNK + co)) * DMODEL + h * 64 + lk * 8;
    float o0[8], o1[8];
    {
        float4 a = *(const float4*)(offp);
        float4 bb = *(const float4*)(offp + 4);
        float4 cc = *(const float4*)(offp + 32);
        float4 dd = *(const float4*)(offp + 36);
        o0[0] = a.x; o0[1] = a.y; o0[2] = a.z; o0[3] = a.w;
        o0[4] = bb.x; o0[5] = bb.y; o0[6] = bb.z; o0[7] = bb.w;
        o1[0] = cc.x; o1[1] = cc.y; o1[2] = cc.z; o1[3] = cc.w;
        o1[4] = dd.x; o1[5] = dd.y; o1[6] = dd.z; o1[7] = dd.w;
    }

    const unsigned short* wpb = WP + ((size_t)h << 11) + lm * 64 + lk * 8;
    bf16x8_t b00 = *(const bf16x8_t*)(wpb);
    bf16x8_t b01 = *(const bf16x8_t*)(wpb + 32);
    bf16x8_t b10 = *(const bf16x8_t*)(wpb + 16 * 64);
    bf16x8_t b11 = *(const bf16x8_t*)(wpb + 16 * 64 + 32);

    f32x4_t acc[4][2];
    float n2p[4];
    #pragma unroll
    for (int i = 0; i < 4; ++i) {
        n2p[i] = 0.f;
        acc[i][0] = f32x4_t{0.f, 0.f, 0.f, 0.f};
        acc[i][1] = f32x4_t{0.f, 0.f, 0.f, 0.f};
    }

    const unsigned short* xbase = X + ((size_t)(b * LSEQ + row0 + lm)) * DMODEL + h * 64 + lk * 8;
    #pragma unroll
    for (int i = 0; i < 4; ++i) {
        const unsigned short* xp = xbase + (size_t)(16 * i) * DMODEL;
        bf16x8_t x0 = *(const bf16x8_t*)(xp);
        bf16x8_t x1 = *(const bf16x8_t*)(xp + 32);
        bf16x8_t xa0, xa1;
        #pragma unroll
        for (int j = 0; j < 8; ++j) {
            float xf = b2f((unsigned short)x0[j]) + o0[j];
            n2p[i] = fmaf(xf, xf, n2p[i]);
            xa0[j] = (short)f2bf(xf);
        }
        #pragma unroll
        for (int j = 0; j < 8; ++j) {
            float xf = b2f((unsigned short)x1[j]) + o1[j];
            n2p[i] = fmaf(xf, xf, n2p[i]);
            xa1[j] = (short)f2bf(xf);
        }
        acc[i][0] = __builtin_amdgcn_mfma_f32_16x16x32_bf16(xa0, b00, acc[i][0], 0, 0, 0);
        acc[i][1] = __builtin_amdgcn_mfma_f32_16x16x32_bf16(xa0, b10, acc[i][1], 0, 0, 0);
        acc[i][0] = __builtin_amdgcn_mfma_f32_16x16x32_bf16(xa1, b01, acc[i][0], 0, 0, 0);
        acc[i][1] = __builtin_amdgcn_mfma_f32_16x16x32_bf16(xa1, b11, acc[i][1], 0, 0, 0);
    }

    #pragma unroll
    for (int i = 0; i < 4; ++i) {
        n2p[i] += __shfl_xor(n2p[i], 16);
        n2p[i] += __shfl_xor(n2p[i], 32);
    }
    if (lane < 16) {
        #pragma unroll
        for (int i = 0; i < 4; ++i) n2buf[w][16 * i + lane] = n2p[i];
    }
    __syncthreads();

    #pragma unroll
    for (int i = 0; i < 4; ++i) {
        f32x4_t n2v = *(const f32x4_t*)&n2buf[w][16 * i + lk * 4];
        float inv[4];
        #pragma unroll
        for (int r = 0; r < 4; ++r) {
            int lr = row0 + 16 * i + lk * 4 + r;
            inv[r] = 1.f / fmaxf(sqrtf(n2v[r]), 1e-12f * (float)(lr + 1));
        }
        #pragma unroll
        for (int j = 0; j < 2; ++j) {
            int col = 16 * j + lm;
            #pragma unroll
            for (int r = 0; r < 4; ++r) {
                int lr = row0 + 16 * i + lk * 4 + r;
                float v = acc[i][j][r] * inv[r];
                if (col < RDIM)
                    eout[(((size_t)(b * NHEAD + h)) * LSEQ + lr) * RDIM + col] = v;
                sbf[((size_t)(b * LSEQ + lr)) * 1024 + h * 64 + z * 32 + col] =
                    (col < RDIM) ? f2bf(v) : (unsigned short)0;
            }
        }
    }
}

// ---------------- host launcher ----------------
extern "C" void kernel_launch(void* const* d_in, const int* in_sizes, int n_in,
                              void* d_out, int out_size, void* d_ws, size_t ws_size,
                              hipStream_t stream)
{
    const float* queries = (const float*)d_in[0];
    const float* keys    = (const float*)d_in[1];
    const float* Wq = (const float*)d_in[3];
    const float* bq = (const float*)d_in[4];
    const float* Wk = (const float*)d_in[5];
    const float* bk = (const float*)d_in[6];
    const float* We = (const float*)d_in[7];
    const float* Wr = (const float*)d_in[8];
    const float* Lam = (const float*)d_in[9];
    const float* Wc = (const float*)d_in[10];
    const float* bc = (const float*)d_in[11];
    const float* Wo = (const float*)d_in[12];
    const float* bo = (const float*)d_in[13];

    float* out = (float*)d_out;                        // [B,L,D]
    float* escore = out + (size_t)16777216;            // [B,H,L,R]
    float* rscore = out + (size_t)24641536;            // [B,H,L,R]
    float* lam_out = out + (size_t)32505856;           // [H,R]

    char* ws = (char*)d_ws;
    unsigned short* sbf = (unsigned short*)ws;                    // 32 MiB bf16 scores [16384][1024]
    unsigned short* Qb  = (unsigned short*)(ws + 33554432);       // 32 MiB bf16 [B,L,D] (cumsum'd)
    unsigned short* Kb  = (unsigned short*)(ws + 67108864);       // 32 MiB
    unsigned short* WqT = (unsigned short*)(ws + 100663296);      // 2 MiB
    unsigned short* WkT = (unsigned short*)(ws + 102760448);      // 2 MiB
    unsigned short* WfT = (unsigned short*)(ws + 104857600);      // 2 MiB [1024][1024]
    float* bias2 = (float*)(ws + 106954752);                      // 4 KiB
    float* partQ = (float*)(ws + 106958848);                      // 512 KiB
    float* partK = (float*)(ws + 107483136);                      // 512 KiB
    unsigned short* WeP = (unsigned short*)(ws + 108007424);      // 64 KiB
    unsigned short* WrP = (unsigned short*)(ws + 108072960);      // 64 KiB
    // total ws use: ~103.2 MiB

    dim3 tb(32, 8);
    transpose_cvt_kernel<<<dim3(32, 32, 2), tb, 0, stream>>>(Wq, Wk, WqT, WkT);
    wpack_kernel<<<dim3(16, 2), 256, 0, stream>>>(We, Wr, WeP, WrP);
    bias2_kernel<<<16, 256, 0, stream>>>(Wo, bc, bo, bias2);
    wfold_kernel<<<dim3(16, 16), 256, 0, stream>>>(Wc, Wo, WfT);

    // fused Q+K projections + causal cumsum in epilogue (writes bf16 cumsum + f32 chunk totals)
    gemm8_kernel<true, true, true, 1024><<<dim3(4, 64, 2), 512, 0, stream>>>(
        queries, keys, WqT, WkT, bq, bk, Qb, Kb, partQ, partK, 1024);

    chunk_offsets_kernel<<<dim3(16, 2), 256, 0, stream>>>(partQ, partK);

    score_kernel<<<dim3(16, 64, 2), 256, 0, stream>>>(Qb, Kb, partQ, partK, WeP, WrP,
                                                      escore, rscore, sbf);

    // final GEMM: K=1024 padded (2-half schedule, rolled loop)
    gemm8_kernel<false, false, false, 1024><<<dim3(4, 64, 1), 512, 0, stream>>>(
        sbf, sbf, WfT, WfT, bias2, bias2, out, out, nullptr, nullptr, 1024);

    hipMemcpyAsync(lam_out, Lam, 480 * sizeof(float), hipMemcpyDeviceToDevice, stream);
}